// Round 9
// baseline (14.106 us; speedup 1.0000x reference)
//
#include <hip/hip_runtime.h>
#include <math.h>

namespace {

typedef _Float16 f16;
typedef _Float16 f16x8 __attribute__((ext_vector_type(8)));
typedef _Float16 f16x4 __attribute__((ext_vector_type(4)));
typedef float    f32x4 __attribute__((ext_vector_type(4)));

constexpr int D  = 32;
constexpr int H  = 128;
constexpr int S2 = 152;   // f16 stride for h/r/q bufs: 304B row, 76dw%32=12 -> 2-way (free)
constexpr int S1 = 40;    // f16 stride for v buf
constexpr int THREADS = 256;   // 4 waves
constexpr int BPB = 64;        // batch rows per block (16 per wave)

__device__ __forceinline__ float fast_tanh(float z) {
  float e = __expf(2.0f * z);
  return 1.0f - 2.0f * __builtin_amdgcn_rcpf(e + 1.0f);
}

__device__ __forceinline__ f32x4 mfma16(f16x8 a, f16x8 b, f32x4 c) {
  return __builtin_amdgcn_mfma_f32_16x16x32_f16(a, b, c, 0, 0, 0);
}

// R7/R8 lesson: LDS weight-staging (scalar b16 transpose scatter, ~10K LDS instr
// per block + 1K b128 c_k reads) dominated the 25K-cycle runtime — each wave
// reads each weight fragment ONCE, so staging is pure overhead. Here ALL MFMA
// A-fragments come straight from global (32KB weights are L2-resident):
// contiguous orientations as 2x dwordx4, transposed ones as 8 coalesced scalar
// dwords. LDS holds only per-wave h/r/v/q buffers (in-order per wave -> the
// only barrier is after the c_k precompute). Batch = MFMA col throughout (R7).
__global__ __launch_bounds__(THREADS, 1) void fpe_g(
    const float* __restrict__ xg, const float* __restrict__ tg,
    const float* __restrict__ betag, const float* __restrict__ W1g,
    const float* __restrict__ b1g, const float* __restrict__ W2g,
    const float* __restrict__ b2g, float* __restrict__ out, int Btot)
{
  __shared__ alignas(16) f16 hbuf[4][16 * S2];  // h, then q (reused)
  __shared__ alignas(16) f16 rbuf[4][16 * S2];  // r = (1-h^2) .* W1[32,:]
  __shared__ alignas(16) f16 vbuf[4][16 * S1];  // v = 2s + x
  __shared__ alignas(16) float cks[H];          // c_k = sum_j W1[j,k] W2[k,j]

  const int tid = threadIdx.x;
  const int wv  = tid >> 6;
  const int ln  = tid & 63;
  const int col = ln & 15;       // batch column / A-row index
  const int g4  = ln >> 4;       // 16-lane group
  const int b0  = blockIdx.x * BPB + wv * 16;
  const int batch = min(b0 + col, Btot - 1);

  // ---- per-element loads (B-frag of X^T + C-layout x slices)
  const float* xrow = xg + (size_t)batch * D;
  const float4 xk0 = *(const float4*)(xrow + 8 * g4);
  const float4 xk1 = *(const float4*)(xrow + 8 * g4 + 4);
  const float4 xc0 = *(const float4*)(xrow + 4 * g4);        // om=0 rows
  const float4 xc1 = *(const float4*)(xrow + 16 + 4 * g4);   // om=1 rows
  const float tval  = tg[batch];
  const float hbeta = 0.5f * betag[batch];

  f16x8 bx;
  bx[0] = (f16)xk0.x; bx[1] = (f16)xk0.y; bx[2] = (f16)xk0.z; bx[3] = (f16)xk0.w;
  bx[4] = (f16)xk1.x; bx[5] = (f16)xk1.y; bx[6] = (f16)xk1.z; bx[7] = (f16)xk1.w;

  // ---- c_k precompute (once per block, 2 waves; others wait at the barrier)
  if (tid < H) {
    const float* w2row = W2g + tid * D;
    float c0 = 0.f, c1 = 0.f;
    #pragma unroll
    for (int j = 0; j < D; j += 2) {
      c0 = fmaf(W1g[j * H + tid],       w2row[j],     c0);
      c1 = fmaf(W1g[(j + 1) * H + tid], w2row[j + 1], c1);
    }
    cks[tid] = c0 + c1;
  }
  __syncthreads();

  f16* hb = hbuf[wv];
  f16* rb = rbuf[wv];
  f16* vb = vbuf[wv];

  // ===== Z: z = W1^T x (+ b1 + t-row), h = tanh(z), r -> LDS
  float hC[8][4];
  #pragma unroll 2
  for (int hm = 0; hm < 8; ++hm) {
    // A-frag: W1T[k_h=16hm+col][i=8g4+j] = W1[8g4+j][16hm+col], 8 scalar loads
    const float* ap = W1g + (8 * g4) * H + 16 * hm + col;
    f16x8 af;
    #pragma unroll
    for (int j = 0; j < 8; ++j) af[j] = (f16)ap[j * H];
    f32x4 z = mfma16(af, bx, f32x4{0.f, 0.f, 0.f, 0.f});
    const float4 b1v = *(const float4*)(b1g + 16 * hm + 4 * g4);
    const float4 wtv = *(const float4*)(W1g + D * H + 16 * hm + 4 * g4);
    f16x4 hv, rv;
    #pragma unroll
    for (int r = 0; r < 4; ++r) {
      float zz = z[r] + ((const float*)&b1v)[r] + ((const float*)&wtv)[r] * tval;
      float hh = fast_tanh(zz);
      hC[hm][r] = hh;
      hv[r] = (f16)hh;
      rv[r] = (f16)(fmaf(-hh, hh, 1.0f) * ((const float*)&wtv)[r]);
    }
    *(f16x4*)&hb[col * S2 + 16 * hm + 4 * g4] = hv;
    *(f16x4*)&rb[col * S2 + 16 * hm + 4 * g4] = rv;
  }

  // ===== S/D: s = W2^T h + b2 ; dsdt = W2^T r   (K=128)
  f32x4 sT[2] = {{0.f,0.f,0.f,0.f}, {0.f,0.f,0.f,0.f}};
  f32x4 dT[2] = {{0.f,0.f,0.f,0.f}, {0.f,0.f,0.f,0.f}};
  #pragma unroll 2
  for (int ks = 0; ks < 4; ++ks) {
    f16x8 hvf = *(const f16x8*)&hb[col * S2 + 32 * ks + 8 * g4];
    f16x8 rvf = *(const f16x8*)&rb[col * S2 + 32 * ks + 8 * g4];
    #pragma unroll
    for (int om = 0; om < 2; ++om) {
      // A-frag: W2T[j=16om+col][k=32ks+8g4+jj] = W2[k][16om+col], 8 scalar loads
      const float* ap = W2g + (32 * ks + 8 * g4) * D + 16 * om + col;
      f16x8 af;
      #pragma unroll
      for (int jj = 0; jj < 8; ++jj) af[jj] = (f16)ap[jj * D];
      sT[om] = mfma16(af, hvf, sT[om]);
      dT[om] = mfma16(af, rvf, dT[om]);
    }
  }
  // s += b2 ; v = 2s + x -> vbuf
  #pragma unroll
  for (int om = 0; om < 2; ++om) {
    const float4 b2v = *(const float4*)(b2g + 16 * om + 4 * g4);
    const float4 xcv = om ? xc1 : xc0;
    f16x4 vv;
    #pragma unroll
    for (int r = 0; r < 4; ++r) {
      sT[om][r] += ((const float*)&b2v)[r];
      vv[r] = (f16)fmaf(2.0f, sT[om][r], ((const float*)&xcv)[r]);
    }
    *(f16x4*)&vb[col * S1 + 16 * om + 4 * g4] = vv;
  }

  // ===== M: m = W2 v (K=32); q = (1-h^2).*(m - 2c.*h) -> hbuf (h dead)
  {
    f16x8 bv = *(const f16x8*)&vb[col * S1 + 8 * g4];
    #pragma unroll 2
    for (int hm = 0; hm < 8; ++hm) {
      // A-frag: W2R[k_h=16hm+col][j=8g4..+7], contiguous
      const float* ap = W2g + (16 * hm + col) * D + 8 * g4;
      const float4 a0 = *(const float4*)ap;
      const float4 a1 = *(const float4*)(ap + 4);
      f16x8 af;
      af[0]=(f16)a0.x; af[1]=(f16)a0.y; af[2]=(f16)a0.z; af[3]=(f16)a0.w;
      af[4]=(f16)a1.x; af[5]=(f16)a1.y; af[6]=(f16)a1.z; af[7]=(f16)a1.w;
      f32x4 m = mfma16(af, bv, f32x4{0.f, 0.f, 0.f, 0.f});
      const float4 cv = *(const float4*)&cks[16 * hm + 4 * g4];
      f16x4 qv;
      #pragma unroll
      for (int r = 0; r < 4; ++r) {
        float hh = hC[hm][r];
        float mm = fmaf(-2.0f * ((const float*)&cv)[r], hh, m[r]);
        qv[r] = (f16)(fmaf(-hh, hh, 1.0f) * mm);
      }
      *(f16x4*)&hb[col * S2 + 16 * hm + 4 * g4] = qv;
    }
  }

  // ===== G: grad-part = W1x q (K=128)
  f32x4 gT[2] = {{0.f,0.f,0.f,0.f}, {0.f,0.f,0.f,0.f}};
  #pragma unroll 2
  for (int ks = 0; ks < 4; ++ks) {
    f16x8 q8 = *(const f16x8*)&hb[col * S2 + 32 * ks + 8 * g4];
    #pragma unroll
    for (int om = 0; om < 2; ++om) {
      // A-frag: W1X[j=16om+col][k=32ks+8g4..+7], contiguous
      const float* ap = W1g + (16 * om + col) * H + 32 * ks + 8 * g4;
      const float4 a0 = *(const float4*)ap;
      const float4 a1 = *(const float4*)(ap + 4);
      f16x8 af;
      af[0]=(f16)a0.x; af[1]=(f16)a0.y; af[2]=(f16)a0.z; af[3]=(f16)a0.w;
      af[4]=(f16)a1.x; af[5]=(f16)a1.y; af[6]=(f16)a1.z; af[7]=(f16)a1.w;
      gT[om] = mfma16(af, q8, gT[om]);
    }
  }

  // ===== resid = dsdt - hb*(s + grad); L1 mean over j; reduce 4 lane-groups
  float acc = 0.f;
  #pragma unroll
  for (int om = 0; om < 2; ++om)
    #pragma unroll
    for (int r = 0; r < 4; ++r)
      acc += fabsf(dT[om][r] - hbeta * (sT[om][r] + gT[om][r]));
  acc += __shfl_xor(acc, 16);
  acc += __shfl_xor(acc, 32);
  if (ln < 16 && (b0 + ln) < Btot) out[b0 + ln] = acc * (1.0f / 32.0f);
}

} // namespace

extern "C" void kernel_launch(void* const* d_in, const int* in_sizes, int n_in,
                              void* d_out, int out_size, void* d_ws, size_t ws_size,
                              hipStream_t stream) {
  const float* x    = (const float*)d_in[0];
  const float* t    = (const float*)d_in[1];
  const float* beta = (const float*)d_in[2];
  const float* W1   = (const float*)d_in[3];
  const float* b1   = (const float*)d_in[4];
  const float* W2   = (const float*)d_in[5];
  const float* b2   = (const float*)d_in[6];
  float* out = (float*)d_out;

  const int Btot = in_sizes[1];  // t is [B,1]
  const int grid = (Btot + BPB - 1) / BPB;
  hipLaunchKernelGGL(fpe_g, dim3(grid), dim3(THREADS), 0, stream,
                     x, t, beta, W1, b1, W2, b2, out, Btot);
}

// Round 10
// 12.433 us; speedup vs baseline: 1.1345x; 1.1345x over previous
//
#include <hip/hip_runtime.h>
#include <math.h>

namespace {

typedef _Float16 f16;
typedef _Float16 f16x4 __attribute__((ext_vector_type(4)));
typedef _Float16 f16x8 __attribute__((ext_vector_type(8)));
typedef float    f32x4 __attribute__((ext_vector_type(4)));

constexpr int D   = 32;
constexpr int H   = 128;
constexpr int ST1 = 36;    // W1T stride (f16): 18dw rows -> 16 distinct banks, 2-way max (free)
constexpr int ST2 = 136;   // W2T stride (f16): 68dw rows -> ~2-way (free)
constexpr int THREADS = 256;   // 4 waves
constexpr int BPB = 64;        // 16 batch rows per wave

__device__ __forceinline__ float fast_tanh(float z) {
  float e = __expf(2.0f * z);
  return 1.0f - 2.0f * __builtin_amdgcn_rcpf(e + 1.0f);
}

__device__ __forceinline__ f32x4 mfma16(f16x4 a, f16x4 b, f32x4 c) {
  return __builtin_amdgcn_mfma_f32_16x16x16f16(a, b, c, 0, 0, 0);
}

__device__ __forceinline__ f16x4 cvt4(float4 w) {
  return f16x4{(f16)w.x, (f16)w.y, (f16)w.z, (f16)w.w};
}

// R8 (pair-split + barriers) and R9 (global-direct transposed frags) both lost
// to R7 -> the cost is the serial chain: 4 stages x LDS round-trip handoffs.
// KEY: for mfma 16x16x16, the B-frag layout (col=lane&15, k=(lane>>4)*4+r)
// EQUALS the C/D layout. With batch pinned to col, every stage's accumulator
// feeds the next stage's B-operand in-register (2 cvt ops) -- no LDS, no
// shuffles, no barriers in the whole compute chain. K=128 => 8 chained MFMAs
// (4 independent chains in S/D, 2 in G). LDS holds only transposed A-operands
// (W1T, W2T); natural-orientation A-frags (M: W2 rows, G: W1 rows) are
// contiguous float4 straight from L2.
__global__ __launch_bounds__(THREADS, 1) void fpe_k16(
    const float* __restrict__ xg, const float* __restrict__ tg,
    const float* __restrict__ betag, const float* __restrict__ W1g,
    const float* __restrict__ b1g, const float* __restrict__ W2g,
    const float* __restrict__ b2g, float* __restrict__ out, int Btot)
{
  __shared__ alignas(16) f16 W1T[H * ST1];  // [k_h][i]  (A of Z)
  __shared__ alignas(16) f16 W2T[D * ST2];  // [j][k_h]  (A of S/D)
  __shared__ alignas(16) float cks[H];      // c_k = sum_j W1[j,k] W2[k,j]

  const int tid = threadIdx.x;

  // ---- stage transposed weights (f16 scatter), 4 float4 per thread each
  for (int n4 = tid; n4 < (D * H) / 4; n4 += THREADS) {
    float4 w = ((const float4*)W1g)[n4];       // W1[i][k..k+3]
    int flat = n4 * 4, i = flat >> 7, k = flat & 127;
    W1T[(k + 0) * ST1 + i] = (f16)w.x;
    W1T[(k + 1) * ST1 + i] = (f16)w.y;
    W1T[(k + 2) * ST1 + i] = (f16)w.z;
    W1T[(k + 3) * ST1 + i] = (f16)w.w;
  }
  for (int n4 = tid; n4 < (H * D) / 4; n4 += THREADS) {
    float4 w = ((const float4*)W2g)[n4];       // W2[k][j..j+3]
    int flat = n4 * 4, k = flat >> 5, j = flat & 31;
    W2T[(j + 0) * ST2 + k] = (f16)w.x;
    W2T[(j + 1) * ST2 + k] = (f16)w.y;
    W2T[(j + 2) * ST2 + k] = (f16)w.z;
    W2T[(j + 3) * ST2 + k] = (f16)w.w;
  }
  __syncthreads();

  if (tid < H) {                               // c_k: LDS W1T row x global W2 row
    const float4* w2r = (const float4*)(W2g + tid * D);
    float c = 0.f;
    #pragma unroll
    for (int q = 0; q < 4; ++q) {
      f16x8 a = *(const f16x8*)&W1T[tid * ST1 + 8 * q];
      float4 wA = w2r[2 * q], wB = w2r[2 * q + 1];
      c += (float)a[0]*wA.x + (float)a[1]*wA.y + (float)a[2]*wA.z + (float)a[3]*wA.w
         + (float)a[4]*wB.x + (float)a[5]*wB.y + (float)a[6]*wB.z + (float)a[7]*wB.w;
    }
    cks[tid] = c;
  }
  __syncthreads();

  const int wv  = tid >> 6;
  const int ln  = tid & 63;
  const int col = ln & 15;       // batch column (B/C col; A row for its own op)
  const int g4  = ln >> 4;       // k-slice / row-quad group
  const int b0  = blockIdx.x * BPB + wv * 16;
  if (b0 >= Btot) return;
  const int batch = min(b0 + col, Btot - 1);

  const float* xrow = xg + (size_t)batch * D;
  const float4 xc0 = *(const float4*)(xrow + 4 * g4);       // x rows 4g4+r
  const float4 xc1 = *(const float4*)(xrow + 16 + 4 * g4);  // x rows 16+4g4+r
  const float tval  = tg[batch];
  const float hbeta = 0.5f * betag[batch];

  const f16x4 bx0 = cvt4(xc0);   // B-frag of Z, K-step 0
  const f16x4 bx1 = cvt4(xc1);   // K-step 1

  // ===== Z: z = W1^T x + b1 + t*W1[32,:]; h = tanh(z); r = (1-h^2)*W1[32,:]
  float hC[8][4];
  f16x4 h16[8], r16[8];
  #pragma unroll
  for (int hm = 0; hm < 8; ++hm) {
    const f16* wrow = &W1T[(16 * hm + col) * ST1];
    f16x4 a0 = *(const f16x4*)(wrow + 4 * g4);
    f16x4 a1 = *(const f16x4*)(wrow + 16 + 4 * g4);
    f32x4 z = mfma16(a0, bx0, f32x4{0.f, 0.f, 0.f, 0.f});
    z = mfma16(a1, bx1, z);
    const float4 b1v = *(const float4*)(b1g + 16 * hm + 4 * g4);
    const float4 wtv = *(const float4*)(W1g + D * H + 16 * hm + 4 * g4);
    #pragma unroll
    for (int r = 0; r < 4; ++r) {
      float zz = z[r] + ((const float*)&b1v)[r] + ((const float*)&wtv)[r] * tval;
      float hh = fast_tanh(zz);
      hC[hm][r] = hh;
      h16[hm][r] = (f16)hh;
      r16[hm][r] = (f16)(fmaf(-hh, hh, 1.0f) * ((const float*)&wtv)[r]);
    }
  }

  // ===== S/D: s = W2^T h + b2 ; dsdt = W2^T r  (K=128 = 8 chained steps)
  f32x4 sT[2] = {{0.f,0.f,0.f,0.f}, {0.f,0.f,0.f,0.f}};
  f32x4 dT[2] = {{0.f,0.f,0.f,0.f}, {0.f,0.f,0.f,0.f}};
  #pragma unroll
  for (int om = 0; om < 2; ++om) {
    const f16* wrow = &W2T[(16 * om + col) * ST2];
    #pragma unroll
    for (int kk = 0; kk < 8; ++kk) {
      f16x4 a = *(const f16x4*)(wrow + 16 * kk + 4 * g4);
      sT[om] = mfma16(a, h16[kk], sT[om]);
      dT[om] = mfma16(a, r16[kk], dT[om]);
    }
  }
  // s += b2 ; v = 2s + x (B-frag of M, step om)
  f16x4 v16[2];
  #pragma unroll
  for (int om = 0; om < 2; ++om) {
    const float4 b2v = *(const float4*)(b2g + 16 * om + 4 * g4);
    const float4 xcv = om ? xc1 : xc0;
    #pragma unroll
    for (int r = 0; r < 4; ++r) {
      sT[om][r] += ((const float*)&b2v)[r];
      v16[om][r] = (f16)fmaf(2.0f, sT[om][r], ((const float*)&xcv)[r]);
    }
  }

  // ===== M: m = W2 v (K=32); q = (1-h^2).*(m - 2c.*h)  (B-frag of G, step hm)
  f16x4 q16[8];
  #pragma unroll
  for (int hm = 0; hm < 8; ++hm) {
    const float* wrow = W2g + (16 * hm + col) * D;
    f32x4 acc = mfma16(cvt4(*(const float4*)(wrow + 4 * g4)),      v16[0],
                       f32x4{0.f, 0.f, 0.f, 0.f});
    acc = mfma16(cvt4(*(const float4*)(wrow + 16 + 4 * g4)),       v16[1], acc);
    const float4 cv = *(const float4*)&cks[16 * hm + 4 * g4];
    #pragma unroll
    for (int r = 0; r < 4; ++r) {
      float hh = hC[hm][r];
      float mm = fmaf(-2.0f * ((const float*)&cv)[r], hh, acc[r]);
      q16[hm][r] = (f16)(fmaf(-hh, hh, 1.0f) * mm);
    }
  }

  // ===== G: grad-part = W1x q (K=128 = 8 chained steps)
  f32x4 gT[2] = {{0.f,0.f,0.f,0.f}, {0.f,0.f,0.f,0.f}};
  #pragma unroll
  for (int om = 0; om < 2; ++om) {
    const float* wrow = W1g + (16 * om + col) * H;
    #pragma unroll
    for (int ks = 0; ks < 8; ++ks)
      gT[om] = mfma16(cvt4(*(const float4*)(wrow + 16 * ks + 4 * g4)),
                      q16[ks], gT[om]);
  }

  // ===== resid = dsdt - hb*(s + grad); L1 mean; reduce over g4 groups
  float acc = 0.f;
  #pragma unroll
  for (int om = 0; om < 2; ++om)
    #pragma unroll
    for (int r = 0; r < 4; ++r)
      acc += fabsf(dT[om][r] - hbeta * (sT[om][r] + gT[om][r]));
  acc += __shfl_xor(acc, 16);
  acc += __shfl_xor(acc, 32);
  if (ln < 16 && (b0 + ln) < Btot) out[b0 + ln] = acc * (1.0f / 32.0f);
}

} // namespace

extern "C" void kernel_launch(void* const* d_in, const int* in_sizes, int n_in,
                              void* d_out, int out_size, void* d_ws, size_t ws_size,
                              hipStream_t stream) {
  const float* x    = (const float*)d_in[0];
  const float* t    = (const float*)d_in[1];
  const float* beta = (const float*)d_in[2];
  const float* W1   = (const float*)d_in[3];
  const float* b1   = (const float*)d_in[4];
  const float* W2   = (const float*)d_in[5];
  const float* b2   = (const float*)d_in[6];
  float* out = (float*)d_out;

  const int Btot = in_sizes[1];  // t is [B,1]
  const int grid = (Btot + BPB - 1) / BPB;
  hipLaunchKernelGGL(fpe_k16, dim3(grid), dim3(THREADS), 0, stream,
                     x, t, beta, W1, b1, W2, b2, out, Btot);
}